// Round 4
// baseline (474.150 us; speedup 1.0000x reference)
//
#include <hip/hip_runtime.h>

// SpecEMA: y[b,c,t,f] = x[b,c,t,f] / sqrt(s[b,t,f]),
//   s_t = ALPHA*s_{t-1} + (1-ALPHA)*(x[b,0,t,f]^2 + x[b,1,t,f]^2), s_{-1}=state[f]
// Outputs: y [64,2,4000,96] then final_state [64,1,96], flat-concatenated in d_out.
//
// R4: single-pass fused kernel (ticket-ordered decoupled lookback).
// R3 showed occupancy is exhausted (2x waves/CU = -6 us) and the fill kernel
// saturates HBM at 10% occupancy; the remaining waste was the hard barrier
// between the read-only phase1 and write-bound phase3. Fusing lets early-k
// blocks write y while late-k blocks still stream-read x.
//
// Safety argument (no deadlock, dispatch-order independent):
//  - block's virtual id = atomicAdd ticket => ticket order == start order.
//  - every block publishes its chunk aggregate B_k BEFORE its first wait;
//    a block only waits on lower tickets => by induction all waits terminate.
// Cross-XCD visibility: bws values move via agent-scope relaxed 64-bit atomic
// ld/st (bypass non-coherent per-XCD L2, meet at the coherence point); flag
// store is RELEASE-agent (drains data stores first); readers spin RELAXED and
// order via control dependency + __syncthreads. No cache-wide inv/wb ops, so
// x stays L2-hot for the normalize pass.

namespace {
constexpr int Bdim = 64, Cdim = 2, Tdim = 4000, Fdim = 96;
constexpr int K = 200, L = 20;             // T = K * L
constexpr int FG = Fdim / 4;               // 24 float4 groups per (b, c, t)
constexpr int CHAINS = Bdim * FG;          // 1536 float4-chains
constexpr int CB = CHAINS / 256;           // 6 chain-blocks of 256 threads
constexpr int NBLK = CB * K;               // 1200 workgroups
constexpr float kAlpha = 0.99f;
constexpr float kOneMinusAlpha = 0.01f;    // float(1.0 - 0.99)
constexpr float kAlphaL = 0.81790694f;     // 0.99^20

typedef float v4f __attribute__((ext_vector_type(4)));
typedef unsigned long long u64;

__device__ __forceinline__ v4f ld4(const float* p) {
  return *reinterpret_cast<const v4f*>(p);
}

union V4u {
  v4f v;
  u64 q[2];
};

// Agent-scope (device) relaxed 16B store/load as 2x u64 atomics: these bypass
// the per-XCD L2 and hit the coherence point, so no wbl2/inv fences needed.
__device__ __forceinline__ void agent_store_v4(float* p, v4f val) {
  V4u u;
  u.v = val;
  u64* q = reinterpret_cast<u64*>(p);
  __hip_atomic_store(&q[0], u.q[0], __ATOMIC_RELAXED, __HIP_MEMORY_SCOPE_AGENT);
  __hip_atomic_store(&q[1], u.q[1], __ATOMIC_RELAXED, __HIP_MEMORY_SCOPE_AGENT);
}
__device__ __forceinline__ v4f agent_load_v4(const float* p) {
  const u64* q = reinterpret_cast<const u64*>(p);
  V4u u;
  u.q[0] = __hip_atomic_load(&q[0], __ATOMIC_RELAXED, __HIP_MEMORY_SCOPE_AGENT);
  u.q[1] = __hip_atomic_load(&q[1], __ATOMIC_RELAXED, __HIP_MEMORY_SCOPE_AGENT);
  return u.v;
}
}  // namespace

// Zero the ticket counter + NBLK flags (workspace is poisoned each iteration).
__global__ __launch_bounds__(256) void spec_ema_zero(unsigned int* flags) {
  const int i = blockIdx.x * 256 + threadIdx.x;
  if (i < NBLK + 1) flags[i] = 0u;
}

__global__ __launch_bounds__(256) void spec_ema_fused(
    const float* __restrict__ x, const float* __restrict__ state,
    float* __restrict__ bws, unsigned int* __restrict__ flags,
    float* __restrict__ out) {
  __shared__ unsigned int s_vb;
  if (threadIdx.x == 0) s_vb = atomicAdd(&flags[0], 1u);
  __syncthreads();
  const int vb = (int)s_vb;
  const int k = vb / CB, cb = vb % CB;
  const int chain = cb * 256 + (int)threadIdx.x;
  const int b = chain / FG, fg = chain % FG;
  unsigned int* fl = flags + 1;

  const size_t base =
      ((size_t)b * Cdim * Tdim + (size_t)k * L) * Fdim + (size_t)fg * 4;
  const float* p0 = x + base;                       // c = 0
  const float* p1 = p0 + (size_t)Tdim * Fdim;       // c = 1

  // ---- local pass: chunk aggregate B_k (EMA from s = 0) ----
  v4f sB = 0.0f;
#pragma unroll 10
  for (int j = 0; j < L; ++j) {
    v4f x0 = ld4(p0 + (size_t)j * Fdim);
    v4f x1 = ld4(p1 + (size_t)j * Fdim);
    sB = sB * kAlpha + (x0 * x0 + x1 * x1) * kOneMinusAlpha;
  }
  agent_store_v4(bws + ((size_t)k * CHAINS + chain) * 4, sB);
  __syncthreads();  // drains vmcnt(0): all lanes' bws stores at coherence pt
  if (threadIdx.x == 0)
    __hip_atomic_store(&fl[vb], 1u, __ATOMIC_RELEASE, __HIP_MEMORY_SCOPE_AGENT);

  // ---- lookback: s_in(k) = a^(kL) s0 + sum_{m<k} a^((k-1-m)L) B_m ----
  v4f s = ld4(state + (size_t)fg * 4);
  if (k > 0) {
    // thread m (< k <= 199 < 256) waits on predecessor m's flag
    if ((int)threadIdx.x < k) {
      while (__hip_atomic_load(&fl[(int)threadIdx.x * CB + cb],
                               __ATOMIC_RELAXED,
                               __HIP_MEMORY_SCOPE_AGENT) == 0u)
        __builtin_amdgcn_s_sleep(4);
    }
    __syncthreads();
#pragma unroll 4
    for (int m = 0; m < k; ++m) {
      v4f bm = agent_load_v4(bws + ((size_t)m * CHAINS + chain) * 4);
      s = s * kAlphaL + bm;
    }
  }

  // ---- main pass: scan chunk with true s_in, normalize, NT-store ----
  float* q0 = out + base;
  float* q1 = q0 + (size_t)Tdim * Fdim;
#pragma unroll 5
  for (int j = 0; j < L; ++j) {
    v4f x0 = ld4(p0 + (size_t)j * Fdim);   // L2-hot from local pass
    v4f x1 = ld4(p1 + (size_t)j * Fdim);
    v4f abs2 = x0 * x0 + x1 * x1;
    s = s * kAlpha + abs2 * kOneMinusAlpha;
    v4f r;
    r.x = rsqrtf(s.x);
    r.y = rsqrtf(s.y);
    r.z = rsqrtf(s.z);
    r.w = rsqrtf(s.w);
    __builtin_nontemporal_store(x0 * r,
        reinterpret_cast<v4f*>(q0 + (size_t)j * Fdim));
    __builtin_nontemporal_store(x1 * r,
        reinterpret_cast<v4f*>(q1 + (size_t)j * Fdim));
  }

  if (k == K - 1) {
    // final_state [64, 1, 96] appended after y
    *reinterpret_cast<v4f*>(out + (size_t)Bdim * Cdim * Tdim * Fdim +
                            (size_t)b * Fdim + (size_t)fg * 4) = s;
  }
}

extern "C" void kernel_launch(void* const* d_in, const int* in_sizes, int n_in,
                              void* d_out, int out_size, void* d_ws, size_t ws_size,
                              hipStream_t stream) {
  const float* x = (const float*)d_in[0];      // [64, 2, 4000, 96] f32
  const float* state = (const float*)d_in[1];  // [1, 1, 96] f32
  float* out = (float*)d_out;
  // ws layout: bws (CHAINS*K float4 = 4.92 MB), then ticket+flags (1201 u32)
  float* bws = (float*)d_ws;
  unsigned int* flags =
      (unsigned int*)((char*)d_ws + (size_t)CHAINS * K * 16);

  spec_ema_zero<<<(NBLK + 1 + 255) / 256, 256, 0, stream>>>(flags);
  spec_ema_fused<<<NBLK, 256, 0, stream>>>(x, state, bws, flags, out);
}